// Round 7
// baseline (191.927 us; speedup 1.0000x reference)
//
#include <hip/hip_runtime.h>
#include <hip/hip_bf16.h>
#include <stdint.h>

#define B_ 2
#define N_ 2048
#define DIM_ 1024
#define HEADS_ 16
#define DH_ 64
#define EPS_ 1e-5f

typedef __attribute__((ext_vector_type(4))) float f32x4;
typedef __attribute__((ext_vector_type(8))) __bf16 bf16x8;
typedef __attribute__((ext_vector_type(4))) unsigned int u32x4;

__device__ __forceinline__ f32x4 mfma16(bf16x8 a, bf16x8 b, f32x4 c) {
  return __builtin_amdgcn_mfma_f32_16x16x32_bf16(a, b, c, 0, 0, 0);
}

__device__ __forceinline__ unsigned short f2bf(float x) {
  unsigned int u = __builtin_bit_cast(unsigned int, x);
  u += 0x7fffu + ((u >> 16) & 1u);
  return (unsigned short)(u >> 16);
}

__device__ __forceinline__ unsigned int cvt_pk_bf16(float lo, float hi) {
  unsigned int r;
  asm("v_cvt_pk_bf16_f32 %0, %1, %2" : "=v"(r) : "v"(lo), "v"(hi));
  return r;
}

__device__ __forceinline__ bf16x8 ld_frag(const unsigned short* p) {
  u32x4 v = *reinterpret_cast<const u32x4*>(p);
  return __builtin_bit_cast(bf16x8, v);
}

__device__ __forceinline__ void gload_lds16(const unsigned short* g, unsigned short* l) {
  __builtin_amdgcn_global_load_lds((const __attribute__((address_space(1))) void*)g,
                                   (__attribute__((address_space(3))) void*)l, 16, 0, 0);
}

// ---------------- LayerNorm over sequence axis ----------------
__global__ __launch_bounds__(256) void ln_part(const float* __restrict__ x,
                                               float* __restrict__ ps,
                                               float* __restrict__ pss) {
  const int d = blockIdx.x * 256 + threadIdx.x;
  const int b = blockIdx.y >> 4, sp = blockIdx.y & 15;
  const float* xp = x + (size_t)(b * N_ + sp * 128) * DIM_ + d;
  float s = 0.f, ss = 0.f;
  for (int i = 0; i < 128; ++i) {
    float v = xp[(size_t)i * DIM_];
    s += v;
    ss += v * v;
  }
  int c = b * DIM_ + d;
  ps[sp * (B_ * DIM_) + c] = s;
  pss[sp * (B_ * DIM_) + c] = ss;
}

__global__ void ln_fin(const float* __restrict__ ps, const float* __restrict__ pss,
                       const float* __restrict__ g, float* __restrict__ meanA,
                       float* __restrict__ sclA) {
  int c = blockIdx.x * 256 + threadIdx.x;
  float s = 0.f, ss = 0.f;
#pragma unroll
  for (int sp = 0; sp < 16; ++sp) {
    s += ps[sp * (B_ * DIM_) + c];
    ss += pss[sp * (B_ * DIM_) + c];
  }
  float m = s * (1.f / N_);
  float v = ss * (1.f / N_) - m * m;
  meanA[c] = m;
  sclA[c] = rsqrtf(fmaxf(v, EPS_)) * g[c & (DIM_ - 1)];
}

__global__ __launch_bounds__(256) void ln_apply(const float* __restrict__ x,
                                                const float* __restrict__ meanA,
                                                const float* __restrict__ sclA,
                                                unsigned short* __restrict__ xn) {
  size_t t = (size_t)blockIdx.x * 256 + threadIdx.x;
  size_t base = t * 8;
  int d0 = (int)(base & (DIM_ - 1));
  int b = base >= (size_t)N_ * DIM_;
  int c = b * DIM_ + d0;
  const float4* xp = reinterpret_cast<const float4*>(x + base);
  const float4* mp = reinterpret_cast<const float4*>(meanA + c);
  const float4* sp = reinterpret_cast<const float4*>(sclA + c);
  float4 x0 = xp[0], x1 = xp[1];
  float4 m0 = mp[0], m1 = mp[1];
  float4 s0 = sp[0], s1 = sp[1];
  union {
    unsigned short u[8];
    u32x4 v;
  } o;
  o.u[0] = f2bf((x0.x - m0.x) * s0.x);
  o.u[1] = f2bf((x0.y - m0.y) * s0.y);
  o.u[2] = f2bf((x0.z - m0.z) * s0.z);
  o.u[3] = f2bf((x0.w - m0.w) * s0.w);
  o.u[4] = f2bf((x1.x - m1.x) * s1.x);
  o.u[5] = f2bf((x1.y - m1.y) * s1.y);
  o.u[6] = f2bf((x1.z - m1.z) * s1.z);
  o.u[7] = f2bf((x1.w - m1.w) * s1.w);
  *reinterpret_cast<u32x4*>(xn + base) = o.v;
}

// ---------------- fp32 -> bf16 weight cast (optional scale) ----------------
__global__ __launch_bounds__(256) void cast_bf16(const float* __restrict__ src,
                                                 unsigned short* __restrict__ dst, float scale) {
  size_t t = (size_t)blockIdx.x * 256 + threadIdx.x;
  size_t base = t * 8;
  const float4* sp = reinterpret_cast<const float4*>(src + base);
  float4 a = sp[0], b4 = sp[1];
  union {
    unsigned short u[8];
    u32x4 v;
  } o;
  o.u[0] = f2bf(a.x * scale);
  o.u[1] = f2bf(a.y * scale);
  o.u[2] = f2bf(a.z * scale);
  o.u[3] = f2bf(a.w * scale);
  o.u[4] = f2bf(b4.x * scale);
  o.u[5] = f2bf(b4.y * scale);
  o.u[6] = f2bf(b4.z * scale);
  o.u[7] = f2bf(b4.w * scale);
  *reinterpret_cast<u32x4*>(dst + base) = o.v;
}

// ---------------- GEMM: C[M,Nc] = A[M,K]bf16 * W[Nc,K]bf16^T ----------------
template <bool OUT_F32>
__global__ __launch_bounds__(256) void gemm_bt(const unsigned short* __restrict__ A,
                                               const unsigned short* __restrict__ W,
                                               void* __restrict__ Cout, int K, int ldc) {
  __shared__ unsigned short sA[128 * 64];
  __shared__ unsigned short sB[128 * 64];
  const int tid = threadIdx.x, lane = tid & 63, w = tid >> 6;
  const int wm = w >> 1, wn = w & 1;
  const int l15 = lane & 15, l4 = lane >> 4;
  const int m0 = blockIdx.y * 128, n0 = blockIdx.x * 128;
  f32x4 acc[4][4] = {};
  for (int kt = 0; kt < K; kt += 64) {
    __syncthreads();
#pragma unroll
    for (int p = 0; p < 4; ++p) {
      int flat = p * 256 + tid;
      int row = flat >> 3, c = flat & 7;
      int cs = c ^ (row & 7);
      gload_lds16(A + (size_t)(m0 + row) * K + kt + cs * 8, sA + (size_t)(p * 256 + w * 64) * 8);
      gload_lds16(W + (size_t)(n0 + row) * K + kt + cs * 8, sB + (size_t)(p * 256 + w * 64) * 8);
    }
    __syncthreads();
#pragma unroll
    for (int kk = 0; kk < 2; ++kk) {
      bf16x8 af[4], bfr[4];
#pragma unroll
      for (int i = 0; i < 4; ++i) {
        int rowA = wm * 64 + i * 16 + l15;
        af[i] = ld_frag(sA + rowA * 64 + (((kk * 4 + l4) ^ (rowA & 7)) * 8));
        int rowB = wn * 64 + i * 16 + l15;
        bfr[i] = ld_frag(sB + rowB * 64 + (((kk * 4 + l4) ^ (rowB & 7)) * 8));
      }
#pragma unroll
      for (int i = 0; i < 4; ++i)
#pragma unroll
        for (int j = 0; j < 4; ++j) acc[i][j] = mfma16(af[i], bfr[j], acc[i][j]);
    }
  }
#pragma unroll
  for (int i = 0; i < 4; ++i)
#pragma unroll
    for (int j = 0; j < 4; ++j)
#pragma unroll
      for (int r = 0; r < 4; ++r) {
        size_t off =
            (size_t)(m0 + wm * 64 + i * 16 + l4 * 4 + r) * ldc + (n0 + wn * 64 + j * 16 + l15);
        if (OUT_F32)
          ((float*)Cout)[off] = acc[i][j][r];
        else
          ((unsigned short*)Cout)[off] = f2bf(acc[i][j][r]);
      }
}

// ---------------- V transpose: qkv v-block -> Vt[b][h][dh][n] ----------------
__global__ __launch_bounds__(256) void transpose_v(const unsigned short* __restrict__ qkv,
                                                   unsigned short* __restrict__ Vt) {
  __shared__ unsigned short tt[64][65];
  const int tid = threadIdx.x;
  const int h = blockIdx.y >> 1, b = blockIdx.y & 1;
  const int n0 = blockIdx.x * 64;
  const unsigned short* src = qkv + (size_t)(b * N_ + n0) * 3072 + 2048 + h * 64;
#pragma unroll
  for (int i = 0; i < 16; ++i) {
    int idx = i * 256 + tid;
    int r = idx >> 6, c = idx & 63;
    tt[r][c] = src[(size_t)r * 3072 + c];
  }
  __syncthreads();
  unsigned short* dst = Vt + (size_t)(b * HEADS_ + h) * 64 * N_ + n0;
#pragma unroll
  for (int i = 0; i < 16; ++i) {
    int idx = i * 256 + tid;
    int dh = idx >> 6, nn = idx & 63;
    dst[(size_t)dh * N_ + nn] = tt[nn][dh];
  }
}

// ---------------- Flash attention -------------------------------------------
// 4 waves x 32 q-rows (TWO Q B-frags per wave): the 8 K-frag + 8 V-frag LDS
// reads per tile now feed 32 MFMAs (2 MFMA per read vs 1 before) - halves
// the per-CU ds_read_b128 serialization that dominated the old structure.
// Bias rides in the score arrays as the MFMA C-operand; K/V double-buffered
// via global_load_lds with counted vmcnt(8) barrier (8 bias loads in flight).
__global__ __launch_bounds__(256, 2) void flash_attn(const unsigned short* __restrict__ qkv,
                                                     const float* __restrict__ bias,
                                                     const unsigned short* __restrict__ Vt,
                                                     unsigned short* __restrict__ Oatt) {
  __shared__ unsigned short sK[2][64 * 64];
  __shared__ unsigned short sV[2][64 * 64];
  __shared__ unsigned short sP[4 * 32 * 64];  // per-wave 32q x 64k

  const int tid = threadIdx.x, lane = tid & 63, w = tid >> 6;  // w in 0..3
  const int l15 = lane & 15, l4 = lane >> 4;
  // XCD swizzle: bh = id&31 -> (b,h); id%8 = h%8 so both b of a head (and all
  // its i-blocks) share an XCD -> bias/K/V L2-resident & deduped.
  const int r = blockIdx.x;
  const int bh = r & 31, iblk = r >> 5;
  const int h = bh & 15, b = bh >> 4;
  const int i0 = iblk * 128;
  const int qbase = i0 + w * 32;

  const unsigned short* Kg = qkv + (size_t)b * N_ * 3072 + 1024 + h * 64;
  const unsigned short* VtB = Vt + (size_t)(b * HEADS_ + h) * 64 * N_;
  const float* bias_q0 =
      bias + (size_t)h * N_ * N_ + (size_t)(qbase + l15) * N_ + l4 * 4;
  const float* bias_q1 = bias_q0 + 16 * N_;

  // staging: 256 threads x 2 chunks each for K and V (64 rows x 8 chunks)
  const int row0 = tid >> 3, c0 = tid & 7;
  const int cs0 = c0 ^ (row0 & 7);
  const unsigned short* KgS = Kg + (size_t)row0 * 3072 + cs0 * 8;
  const unsigned short* VtS = VtB + (size_t)row0 * N_ + cs0 * 8;

#define STAGE(BUF, JN)                                                     \
  gload_lds16(KgS + (size_t)(JN) * 3072, sK[BUF] + w * 512);               \
  gload_lds16(KgS + (size_t)(JN) * 3072 + 32 * 3072, sK[BUF] + 2048 + w * 512); \
  gload_lds16(VtS + (JN), sV[BUF] + w * 512);                              \
  gload_lds16(VtS + (JN) + 32 * (size_t)N_, sV[BUF] + 2048 + w * 512);

  // Q straight to registers: q-frag f covers cols q = qbase + f*16 + l15
  bf16x8 qf00, qf01, qf10, qf11;
  {
    const unsigned short* Qg0 =
        qkv + (size_t)(b * N_ + qbase + l15) * 3072 + h * 64 + l4 * 8;
    const unsigned short* Qg1 = Qg0 + (size_t)16 * 3072;
    qf00 = ld_frag(Qg0);
    qf01 = ld_frag(Qg0 + 32);
    qf10 = ld_frag(Qg1);
    qf11 = ld_frag(Qg1 + 32);
  }

  f32x4 o_t[8] = {};          // [f*4+dj]
  f32x4 stA[8], stB[8];       // score/bias ping-pong [f*4+kj]
  float m0_run = -1e30f, l0_run = 0.f;
  float m1_run = -1e30f, l1_run = 0.f;
  const int sw = l15 & 7;

  unsigned int* sPu = reinterpret_cast<unsigned int*>(sP + (size_t)w * 2048);
  const unsigned short* sPw = sP + (size_t)w * 2048;

  // prologue: stage tile 0 + bias tile 0 -> stA
  STAGE(0, 0)
#pragma unroll
  for (int kj = 0; kj < 4; ++kj) {
    stA[kj] = *reinterpret_cast<const f32x4*>(bias_q0 + kj * 16);
    stA[4 + kj] = *reinterpret_cast<const f32x4*>(bias_q1 + kj * 16);
  }
  __syncthreads();

  const int NT = N_ / 64;

#define TILE_BODY(T, CUR, NXT, SC, SN)                                         \
  {                                                                            \
    if ((T) + 1 < NT) {                                                        \
      const size_t jn = (size_t)((T) + 1) * 64;                                \
      STAGE(NXT, jn)                                                           \
      __builtin_amdgcn_sched_barrier(0); /* pin gloads oldest in vmem queue */ \
      _Pragma("unroll") for (int kj = 0; kj < 4; ++kj) {                       \
        SN[kj] = *reinterpret_cast<const f32x4*>(bias_q0 + jn + kj * 16);      \
        SN[4 + kj] = *reinterpret_cast<const f32x4*>(bias_q1 + jn + kj * 16);  \
      }                                                                        \
    }                                                                          \
    const unsigned short* sKc = sK[CUR];                                       \
    const unsigned short* sVc = sV[CUR];                                       \
    /* S^T = K Q^T + bias (bias preloaded into SC = C-operand) */              \
    __builtin_amdgcn_s_setprio(1);                                             \
    _Pragma("unroll") for (int kj = 0; kj < 4; ++kj) {                         \
      int row = kj * 16 + l15;                                                 \
      bf16x8 kf0 = ld_frag(sKc + row * 64 + ((l4 ^ sw) * 8));                  \
      bf16x8 kf1 = ld_frag(sKc + row * 64 + (((4 + l4) ^ sw) * 8));            \
      SC[kj] = mfma16(kf0, qf00, SC[kj]);                                      \
      SC[kj] = mfma16(kf1, qf01, SC[kj]);                                      \
      SC[4 + kj] = mfma16(kf0, qf10, SC[4 + kj]);                              \
      SC[4 + kj] = mfma16(kf1, qf11, SC[4 + kj]);                              \
    }                                                                          \
    __builtin_amdgcn_s_setprio(0);                                             \
    /* online softmax, q-frag 0 (q = qbase + l15) */                           \
    {                                                                          \
      float mx = fmaxf(fmaxf(fmaxf(SC[0][0], SC[0][1]), fmaxf(SC[0][2], SC[0][3])), \
                       fmaxf(fmaxf(SC[1][0], SC[1][1]), fmaxf(SC[1][2], SC[1][3]))); \
      mx = fmaxf(mx, fmaxf(fmaxf(fmaxf(SC[2][0], SC[2][1]), fmaxf(SC[2][2], SC[2][3])), \
                           fmaxf(fmaxf(SC[3][0], SC[3][1]), fmaxf(SC[3][2], SC[3][3])))); \
      mx = fmaxf(mx, __shfl_xor(mx, 16));                                      \
      mx = fmaxf(mx, __shfl_xor(mx, 32));                                      \
      float mn = fmaxf(m0_run, mx);                                            \
      float alpha = __expf(m0_run - mn);                                       \
      float rs = 0.f;                                                          \
      _Pragma("unroll") for (int kj = 0; kj < 4; ++kj) {                       \
        _Pragma("unroll") for (int rr = 0; rr < 4; ++rr) {                     \
          float p = __expf(SC[kj][rr] - mn);                                   \
          SC[kj][rr] = p;                                                      \
          rs += p;                                                             \
        }                                                                      \
      }                                                                        \
      rs += __shfl_xor(rs, 16);                                                \
      rs += __shfl_xor(rs, 32);                                                \
      l0_run = l0_run * alpha + rs;                                            \
      m0_run = mn;                                                             \
      _Pragma("unroll") for (int dj = 0; dj < 4; ++dj) {                       \
        o_t[dj][0] *= alpha;                                                   \
        o_t[dj][1] *= alpha;                                                   \
        o_t[dj][2] *= alpha;                                                   \
        o_t[dj][3] *= alpha;                                                   \
      }                                                                        \
    }                                                                          \
    /* online softmax, q-frag 1 (q = qbase + 16 + l15) */                      \
    {                                                                          \
      float mx = fmaxf(fmaxf(fmaxf(SC[4][0], SC[4][1]), fmaxf(SC[4][2], SC[4][3])), \
                       fmaxf(fmaxf(SC[5][0], SC[5][1]), fmaxf(SC[5][2], SC[5][3]))); \
      mx = fmaxf(mx, fmaxf(fmaxf(fmaxf(SC[6][0], SC[6][1]), fmaxf(SC[6][2], SC[6][3])), \
                           fmaxf(fmaxf(SC[7][0], SC[7][1]), fmaxf(SC[7][2], SC[7][3])))); \
      mx = fmaxf(mx, __shfl_xor(mx, 16));                                      \
      mx = fmaxf(mx, __shfl_xor(mx, 32));                                      \
      float mn = fmaxf(m1_run, mx);                                            \
      float alpha = __expf(m1_run - mn);                                       \
      float rs = 0.f;                                                          \
      _Pragma("unroll") for (int kj = 0; kj < 4; ++kj) {                       \
        _Pragma("unroll") for (int rr = 0; rr < 4; ++rr) {                     \
          float p = __expf(SC[4 + kj][rr] - mn);                               \
          SC[4 + kj][rr] = p;                                                  \
          rs += p;                                                             \
        }                                                                      \
      }                                                                        \
      rs += __shfl_xor(rs, 16);                                                \
      rs += __shfl_xor(rs, 32);                                                \
      l1_run = l1_run * alpha + rs;                                            \
      m1_run = mn;                                                             \
      _Pragma("unroll") for (int dj = 0; dj < 4; ++dj) {                       \
        o_t[4 + dj][0] *= alpha;                                               \
        o_t[4 + dj][1] *= alpha;                                               \
        o_t[4 + dj][2] *= alpha;                                               \
        o_t[4 + dj][3] *= alpha;                                               \
      }                                                                        \
    }                                                                          \
    /* P -> wave-local swizzled LDS, row q-local = f*16 + l15 */               \
    _Pragma("unroll") for (int f = 0; f < 2; ++f) {                            \
      _Pragma("unroll") for (int kj = 0; kj < 4; ++kj) {                       \
        unsigned int v0 = cvt_pk_bf16(SC[f * 4 + kj][0], SC[f * 4 + kj][1]);   \
        unsigned int v1 = cvt_pk_bf16(SC[f * 4 + kj][2], SC[f * 4 + kj][3]);   \
        int cc = (kj * 2 + (l4 >> 1)) ^ sw;                                    \
        uint2 pv;                                                              \
        pv.x = v0;                                                             \
        pv.y = v1;                                                             \
        *reinterpret_cast<uint2*>(sPu + (f * 16 + l15) * 32 + cc * 4 +         \
                                  (l4 & 1) * 2) = pv;                          \
      }                                                                        \
    }                                                                          \
    /* O^T += V^T P^T (8 V reads feed 16 MFMAs) */                             \
    bf16x8 pb00 = ld_frag(sPw + l15 * 64 + ((l4 ^ sw) * 8));                   \
    bf16x8 pb01 = ld_frag(sPw + l15 * 64 + (((4 + l4) ^ sw) * 8));             \
    bf16x8 pb10 = ld_frag(sPw + (16 + l15) * 64 + ((l4 ^ sw) * 8));            \
    bf16x8 pb11 = ld_frag(sPw + (16 + l15) * 64 + (((4 + l4) ^ sw) * 8));      \
    __builtin_amdgcn_s_setprio(1);                                             \
    _Pragma("unroll") for (int dj = 0; dj < 4; ++dj) {                         \
      int row = dj * 16 + l15;                                                 \
      bf16x8 vf0 = ld_frag(sVc + row * 64 + ((l4 ^ sw) * 8));                  \
      bf16x8 vf1 = ld_frag(sVc + row * 64 + (((4 + l4) ^ sw) * 8));            \
      o_t[dj] = mfma16(vf0, pb00, o_t[dj]);                                    \
      o_t[dj] = mfma16(vf1, pb01, o_t[dj]);                                    \
      o_t[4 + dj] = mfma16(vf0, pb10, o_t[4 + dj]);                            \
      o_t[4 + dj] = mfma16(vf1, pb11, o_t[4 + dj]);                            \
    }                                                                          \
    __builtin_amdgcn_s_setprio(0);                                             \
    if ((T) != NT - 1) {                                                       \
      /* drain only the 4 oldest vmem ops (this tile's gload_lds); the 8 */    \
      /* bias loads (newest) stay in flight across the barrier */              \
      asm volatile("s_waitcnt vmcnt(8)" ::: "memory");                         \
      __builtin_amdgcn_s_barrier();                                            \
    }                                                                          \
  }

  for (int t = 0; t < NT; t += 2) {
    TILE_BODY(t, 0, 1, stA, stB)
    TILE_BODY(t + 1, 1, 0, stB, stA)
  }
#undef TILE_BODY
#undef STAGE

  // epilogue: O = O^T / l, store (q-row = qbase + f*16 + l15)
#pragma unroll
  for (int f = 0; f < 2; ++f) {
    float inv = 1.f / (f ? l1_run : l0_run);
    unsigned short* orow =
        Oatt + (size_t)(b * N_ + qbase + f * 16 + l15) * 1024 + h * 64 + l4 * 4;
#pragma unroll
    for (int dj = 0; dj < 4; ++dj) {
      union {
        unsigned short u[4];
        unsigned long long v;
      } pk;
      pk.u[0] = f2bf(o_t[f * 4 + dj][0] * inv);
      pk.u[1] = f2bf(o_t[f * 4 + dj][1] * inv);
      pk.u[2] = f2bf(o_t[f * 4 + dj][2] * inv);
      pk.u[3] = f2bf(o_t[f * 4 + dj][3] * inv);
      *reinterpret_cast<unsigned long long*>(orow + dj * 16) = pk.v;
    }
  }
}

extern "C" void kernel_launch(void* const* d_in, const int* in_sizes, int n_in, void* d_out,
                              int out_size, void* d_ws, size_t ws_size, hipStream_t stream) {
  const float* x = (const float*)d_in[0];
  const float* bias = (const float*)d_in[1];
  const float* g = (const float*)d_in[2];
  const float* wq = (const float*)d_in[3];
  const float* wkv = (const float*)d_in[4];
  const float* wout = (const float*)d_in[5];
  float* out = (float*)d_out;

  float* ps = (float*)d_ws;
  float* pss = ps + 16 * B_ * DIM_;
  float* meanA = pss + 16 * B_ * DIM_;
  float* sclA = meanA + B_ * DIM_;
  unsigned short* xn = (unsigned short*)(sclA + B_ * DIM_);
  unsigned short* Wqkv = xn + (size_t)4096 * 1024;
  unsigned short* WoutB = Wqkv + (size_t)3072 * 1024;
  unsigned short* qkvb = WoutB + (size_t)1024 * 1024;
  unsigned short* Vt = qkvb + (size_t)4096 * 3072;
  unsigned short* Oatt = xn;  // alias: xn dead after QKV GEMM

  ln_part<<<dim3(DIM_ / 256, B_ * 16), 256, 0, stream>>>(x, ps, pss);
  ln_fin<<<dim3((B_ * DIM_) / 256), 256, 0, stream>>>(ps, pss, g, meanA, sclA);
  ln_apply<<<dim3((B_ * N_ * DIM_) / 2048), 256, 0, stream>>>(x, meanA, sclA, xn);
  cast_bf16<<<dim3((DIM_ * DIM_) / 2048), 256, 0, stream>>>(wq, Wqkv, 0.125f);
  cast_bf16<<<dim3((2 * DIM_ * DIM_) / 2048), 256, 0, stream>>>(wkv, Wqkv + (size_t)DIM_ * DIM_,
                                                                1.0f);
  cast_bf16<<<dim3((DIM_ * DIM_) / 2048), 256, 0, stream>>>(wout, WoutB, 1.0f);
  gemm_bt<false><<<dim3(3072 / 128, 4096 / 128), 256, 0, stream>>>(xn, Wqkv, qkvb, DIM_, 3072);
  transpose_v<<<dim3(N_ / 64, B_ * HEADS_), 256, 0, stream>>>(qkvb, Vt);
  flash_attn<<<dim3(512), 256, 0, stream>>>(qkvb, bias, Vt, Oatt);
  gemm_bt<true><<<dim3(1024 / 128, 4096 / 128), 256, 0, stream>>>(Oatt, WoutB, out, DIM_, 1024);
}